// Round 3
// baseline (773.833 us; speedup 1.0000x reference)
//
#include <hip/hip_runtime.h>
#include <hip/hip_bf16.h>

// LSTM B=2048,T=512,I=5,H=128 + linear -> [B,1], fp32 in/out.
// Round 3: f16 single-precision operands (no hi/lo: h in (-1,1), |W|<0.09,
// |x|<6 all f16-safe; rel err 2^-11 < round-2's bf16-W 2^-9), one 1024-thread
// block per CU = two independent 8-batch halves (16 waves -> 4 waves/SIMD for
// latency hiding; round 2 had 2), double-buffered h -> ONE barrier per step,
// bias folded into MFMA via constant-1.0 A column (k=133).
// Per half: wave ww owns gate-quad cols {g*128 + ww*16 + n}; its 4 acc tiles
// are i,f,g,o of 16 hj x 16 m cells; rows m>=8 are zero padding (M=8 tile in
// M=16 MFMA). Cell phase redistributed by shuffles: every lane does 2 cells.

#define HH 128
#define II 5
#define TT 512
#define BT 16      // batches per block = two halves of 8
#define NT 1024    // 16 waves
#define KS 168     // A-row stride in f16 elems (160 used: 128 h + 5 x + 1 one + pad)

typedef __attribute__((ext_vector_type(8))) _Float16 half8;
typedef __attribute__((ext_vector_type(4))) float f32x4;

__device__ __forceinline__ float sigmoid_f(float x) {
    float e = __builtin_amdgcn_exp2f(x * -1.44269504f);
    return __builtin_amdgcn_rcpf(1.0f + e);
}
__device__ __forceinline__ float tanh_f(float x) {
    float e = __builtin_amdgcn_exp2f(x * 2.88539008f);
    return 1.0f - 2.0f * __builtin_amdgcn_rcpf(1.0f + e);
}

__global__ __launch_bounds__(NT)
void lstm_f16(const float* __restrict__ x,      // [B,T,I]
              const float* __restrict__ W_ih,   // [4H,I]
              const float* __restrict__ W_hh,   // [4H,H]
              const float* __restrict__ b_ih,   // [4H]
              const float* __restrict__ b_hh,   // [4H]
              const float* __restrict__ W_lin,  // [H]
              const float* __restrict__ b_lin,  // [1]
              float* __restrict__ out,          // [B]
              int B)
{
    __shared__ __align__(16) _Float16 hbuf[2][2][16][KS]; // [half][buf][row][col]
    __shared__ float hsc[16][132];                        // final-step fp32 h

    const int tid  = threadIdx.x;
    const int b0   = blockIdx.x * BT;
    const int lane = tid & 63;
    const int w    = tid >> 6;        // 0..15
    const int hf   = w >> 3;          // batch half
    const int ww   = w & 7;           // wave within half -> col group
    const int n    = lane & 15;
    const int q    = lane >> 4;
    const int q8   = q * 8;
    const int hcol = ww * 16 + n;     // this wave's hj columns

    // ---- W fragments, f16, B-layout (lane holds W^T[k=q8+e][n]) ------------
    // cols: k<128 -> W_hh; k=128..132 -> W_ih; k=133 -> folded bias; else 0.
    half8 wf[4][5];
    #pragma unroll
    for (int g = 0; g < 4; ++g) {
        const int j = g * HH + hcol;
        #pragma unroll
        for (int kc = 0; kc < 4; ++kc) {
            const float* p = W_hh + (size_t)j * HH + kc * 32 + q8;
            #pragma unroll
            for (int e = 0; e < 8; ++e) wf[g][kc][e] = (_Float16)p[e];
        }
        #pragma unroll
        for (int e = 0; e < 8; ++e) {
            const int k = q8 + e;                 // local col in chunk 4
            float v = 0.0f;
            if (k < II)       v = W_ih[j * II + k];
            else if (k == II) v = b_ih[j] + b_hh[j];
            wf[g][4][e] = (_Float16)v;
        }
    }

    // ---- init LDS: h0=0 everywhere, A[row<8][133]=1.0 (bias column) --------
    for (int idx = tid; idx < 2 * 2 * 16 * KS; idx += NT)
        (&hbuf[0][0][0][0])[idx] = (_Float16)0.0f;
    __syncthreads();
    if (tid < 32) hbuf[tid >> 4][(tid >> 3) & 1][tid & 7][HH + II] = (_Float16)1.0f;

    // ---- x loader: 80 threads, one (bt,i) each -----------------------------
    const int  btx = tid / II, ixx = tid % II;
    const bool xload = tid < BT * II;
    const float* xg = x + ((size_t)(b0 + btx) * TT) * II + ixx;
    if (xload) hbuf[btx >> 3][0][btx & 7][HH + ixx] = (_Float16)xg[0];
    __syncthreads();

    // cell assignment: this lane handles rows m0, m0+1 of its half
    const int m0 = (q & 1) * 4 + (q >> 1) * 2;
    float cc0 = 0.0f, cc1 = 0.0f;

    #pragma unroll 1
    for (int t = 0; t < TT; ++t) {
        const int pb = t & 1;
        float xv = 0.0f;
        const bool pf = xload && (t + 1 < TT);
        if (pf) xv = xg[(size_t)(t + 1) * II];

        // ---- MFMA phase: gates[16m x 16n] per g, bias included -------------
        f32x4 acc[4];
        #pragma unroll
        for (int g = 0; g < 4; ++g)
            #pragma unroll
            for (int e = 0; e < 4; ++e) acc[g][e] = 0.0f;
        #pragma unroll
        for (int kc = 0; kc < 5; ++kc) {
            half8 ah = *reinterpret_cast<const half8*>(&hbuf[hf][pb][n][kc * 32 + q8]);
            #pragma unroll
            for (int g = 0; g < 4; ++g)
                acc[g] = __builtin_amdgcn_mfma_f32_16x16x32_f16(ah, wf[g][kc], acc[g], 0, 0, 0);
        }

        // ---- redistribute: lane (q,n) takes acc[g][rr], rr=(q>>1)*2+j,
        //      from lane (q&1)*16+n = lane&31 ------------------------------
        float gate[4][2];
        #pragma unroll
        for (int g = 0; g < 4; ++g) {
            float t0 = __shfl(acc[g][0], lane & 31, 64);
            float t1 = __shfl(acc[g][1], lane & 31, 64);
            float t2 = __shfl(acc[g][2], lane & 31, 64);
            float t3 = __shfl(acc[g][3], lane & 31, 64);
            const bool lo = lane < 32;           // q<2
            gate[g][0] = lo ? t0 : t2;
            gate[g][1] = lo ? t1 : t3;
        }

        // ---- cell phase: 2 cells/lane, write h(t+1) to the other buffer ----
        #pragma unroll
        for (int jj = 0; jj < 2; ++jj) {
            float iv = sigmoid_f(gate[0][jj]);
            float fv = sigmoid_f(gate[1][jj]);
            float gv = tanh_f(gate[2][jj]);
            float ov = sigmoid_f(gate[3][jj]);
            float& c = jj ? cc1 : cc0;
            c = fv * c + iv * gv;
            float hv = ov * tanh_f(c);
            hbuf[hf][pb ^ 1][m0 + jj][hcol] = (_Float16)hv;
            if (t == TT - 1) hsc[hf * 8 + m0 + jj][hcol] = hv;
        }
        if (pf) hbuf[btx >> 3][pb ^ 1][btx & 7][HH + ixx] = (_Float16)xv;
        __syncthreads();
    }

    // ---- epilogue: out[b0+w] = hsc[w,:] . W_lin + b_lin --------------------
    float p = hsc[w][lane] * W_lin[lane] + hsc[w][lane + 64] * W_lin[lane + 64];
    #pragma unroll
    for (int off = 32; off > 0; off >>= 1) p += __shfl_down(p, off, 64);
    if (lane == 0 && (b0 + w) < B) out[b0 + w] = p + b_lin[0];
}

extern "C" void kernel_launch(void* const* d_in, const int* in_sizes, int n_in,
                              void* d_out, int out_size, void* d_ws, size_t ws_size,
                              hipStream_t stream) {
    const float* x     = (const float*)d_in[0];
    const float* W_ih  = (const float*)d_in[1];
    const float* W_hh  = (const float*)d_in[2];
    const float* b_ih  = (const float*)d_in[3];
    const float* b_hh  = (const float*)d_in[4];
    const float* W_lin = (const float*)d_in[5];
    const float* b_lin = (const float*)d_in[6];
    float* out = (float*)d_out;

    const int B = in_sizes[0] / (TT * II);          // 2048
    const int grid = (B + BT - 1) / BT;             // 128 blocks, 1 per CU
    lstm_f16<<<grid, NT, 0, stream>>>(x, W_ih, W_hh, b_ih, b_hh,
                                      W_lin, b_lin, out, B);
}

// Round 4
// 579.952 us; speedup vs baseline: 1.3343x; 1.3343x over previous
//
#include <hip/hip_runtime.h>

// LSTM B=2048,T=512,I=5,H=128 + linear -> [B,1], fp32 in/out.
// Round 4: BT=8 -> grid=256 (all CUs; rounds 2-3 left half the chip idle).
// x staged entirely in LDS as f16 at start (removes the per-step global load
// whose ~900cyc HBM latency sat on the barrier critical path). No shuffles:
// wave w owns gate-quad cols {g*128 + w*16 + n}; its 4 acc tiles are the
// i,f,g,o gates of its own 16col x 8row cells; lanes q<2 do 4 cells each in
// C-layout registers (lanes q>=2 exec-masked: M rows 8-15 are zero padding).
// A-operand chunk kc=4 (x cols 128..132, bias-1.0 col 133) built in registers
// from one conflict-free ds_read_b128 of xs. One barrier/step (dbuf h).

#define HH 128
#define II 5
#define TT 512
#define BT 8
#define NT 512
#define KS 136             // hbuf row stride in f16 (128 + 8 pad -> stride%32dw=4)
#define XT (TT * 8 + 8)    // xs per-batch stride in f16 (pad kills conflicts)

typedef __attribute__((ext_vector_type(8))) _Float16 half8;
typedef __attribute__((ext_vector_type(4))) float f32x4;

__device__ __forceinline__ float sigmoid_f(float x) {
    float e = __builtin_amdgcn_exp2f(x * -1.44269504f);
    return __builtin_amdgcn_rcpf(1.0f + e);
}
__device__ __forceinline__ float tanh_f(float x) {
    float e = __builtin_amdgcn_exp2f(x * 2.88539008f);
    return 1.0f - 2.0f * __builtin_amdgcn_rcpf(1.0f + e);
}

__global__ __launch_bounds__(NT)
__attribute__((amdgpu_waves_per_eu(2, 2)))   // 256-VGPR budget: round-1 spill guard
void lstm_r4(const float* __restrict__ x,      // [B,T,I]
             const float* __restrict__ W_ih,   // [4H,I]
             const float* __restrict__ W_hh,   // [4H,H]
             const float* __restrict__ b_ih,   // [4H]
             const float* __restrict__ b_hh,   // [4H]
             const float* __restrict__ W_lin,  // [H]
             const float* __restrict__ b_lin,  // [1]
             float* __restrict__ out,          // [B]
             int B)
{
    __shared__ __align__(16) _Float16 hbuf[2][16][KS];  // 8.7 KB, rows 8-15 stay 0
    __shared__ __align__(16) _Float16 xs[BT * XT];      // 65.7 KB, f16 x + pads
    __shared__ float hsc[BT][HH + 4];                   // final-step fp32 h

    const int tid  = threadIdx.x;
    const int b0   = blockIdx.x * BT;
    const int lane = tid & 63;
    const int w    = tid >> 6;        // 0..7 -> col group
    const int n    = lane & 15;       // A row (batch) / D col
    const int q    = lane >> 4;
    const int q8   = q * 8;
    const int hcol = w * 16 + n;      // this wave's hj columns

    // ---- W fragments, f16, B-layout (lane holds W^T[k=q8+e][col n]) --------
    // k<128: W_hh; 128..132: W_ih; 133: folded bias; 134..159: zero.
    half8 wf[4][5];
    #pragma unroll
    for (int g = 0; g < 4; ++g) {
        const int j = g * HH + hcol;
        #pragma unroll
        for (int kc = 0; kc < 4; ++kc) {
            const float* p = W_hh + (size_t)j * HH + kc * 32 + q8;
            #pragma unroll
            for (int e = 0; e < 8; ++e) wf[g][kc][e] = (_Float16)p[e];
        }
        #pragma unroll
        for (int e = 0; e < 8; ++e) {
            const int k = q8 + e;
            float v = 0.0f;
            if (k < II)       v = W_ih[j * II + k];
            else if (k == II) v = b_ih[j] + b_hh[j];
            wf[g][4][e] = (_Float16)v;
        }
    }

    // ---- zero LDS (h0 = 0; xs pads = 0) ------------------------------------
    for (int idx = tid; idx < 2 * 16 * KS; idx += NT)
        (&hbuf[0][0][0])[idx] = (_Float16)0.0f;
    for (int idx = tid; idx < BT * XT; idx += NT)
        xs[idx] = (_Float16)0.0f;
    __syncthreads();

    // ---- stage x: 64 threads per batch, float4 global reads ----------------
    {
        const int lb = tid & 63;
        const int bb = tid >> 6;      // 0..7
        if (b0 + bb < B) {
            const float* xb = x + (size_t)(b0 + bb) * TT * II;
            for (int e = lb * 4; e < TT * II; e += 256) {
                float4 v = *reinterpret_cast<const float4*>(xb + e);
                float vv[4] = {v.x, v.y, v.z, v.w};
                #pragma unroll
                for (int u = 0; u < 4; ++u) {
                    const int ee = e + u;
                    const int t_ = ee / 5, i_ = ee % 5;   // magic-div by const
                    xs[bb * XT + t_ * 8 + i_] = (_Float16)vv[u];
                }
            }
        }
    }
    __syncthreads();

    float cc[4] = {0.f, 0.f, 0.f, 0.f};   // cells (rows q*4+r), lanes q<2 only

    #pragma unroll 1
    for (int t = 0; t < TT; ++t) {
        const int pb = t & 1;

        // A-frag chunk 4 in registers: x cols + bias-1.0 col (rows >=8 zero)
        half8 ax;
        #pragma unroll
        for (int e = 0; e < 8; ++e) ax[e] = (_Float16)0.0f;
        if (q == 0 && n < BT) {
            ax = *reinterpret_cast<const half8*>(&xs[n * XT + t * 8]);
            ax[5] = (_Float16)1.0f;    // bias column k=133 (elems 6,7 are 0 pads)
        }

        f32x4 acc[4];
        #pragma unroll
        for (int g = 0; g < 4; ++g)
            #pragma unroll
            for (int e = 0; e < 4; ++e) acc[g][e] = 0.0f;

        #pragma unroll
        for (int kc = 0; kc < 4; ++kc) {
            half8 ah = *reinterpret_cast<const half8*>(&hbuf[pb][n][kc * 32 + q8]);
            #pragma unroll
            for (int g = 0; g < 4; ++g)
                acc[g] = __builtin_amdgcn_mfma_f32_16x16x32_f16(ah, wf[g][kc], acc[g], 0, 0, 0);
        }
        #pragma unroll
        for (int g = 0; g < 4; ++g)
            acc[g] = __builtin_amdgcn_mfma_f32_16x16x32_f16(ax, wf[g][4], acc[g], 0, 0, 0);

        // ---- cell phase: lanes q<2 own rows 0..7, 4 cells each, in regs ----
        if (q < 2) {
            #pragma unroll
            for (int r = 0; r < 4; ++r) {
                const int m = q * 4 + r;
                float iv = sigmoid_f(acc[0][r]);
                float fv = sigmoid_f(acc[1][r]);
                float gv = tanh_f(acc[2][r]);
                float ov = sigmoid_f(acc[3][r]);
                cc[r] = fv * cc[r] + iv * gv;
                float hv = ov * tanh_f(cc[r]);
                hbuf[pb ^ 1][m][hcol] = (_Float16)hv;
                if (t == TT - 1) hsc[m][hcol] = hv;
            }
        }
        __syncthreads();
    }

    // ---- epilogue: out[b0+w] = hsc[w,:] . W_lin + b_lin --------------------
    float p = hsc[w][lane] * W_lin[lane] + hsc[w][lane + 64] * W_lin[lane + 64];
    #pragma unroll
    for (int off = 32; off > 0; off >>= 1) p += __shfl_down(p, off, 64);
    if (lane == 0 && (b0 + w) < B) out[b0 + w] = p + b_lin[0];
}

extern "C" void kernel_launch(void* const* d_in, const int* in_sizes, int n_in,
                              void* d_out, int out_size, void* d_ws, size_t ws_size,
                              hipStream_t stream) {
    const float* x     = (const float*)d_in[0];
    const float* W_ih  = (const float*)d_in[1];
    const float* W_hh  = (const float*)d_in[2];
    const float* b_ih  = (const float*)d_in[3];
    const float* b_hh  = (const float*)d_in[4];
    const float* W_lin = (const float*)d_in[5];
    const float* b_lin = (const float*)d_in[6];
    float* out = (float*)d_out;

    const int B = in_sizes[0] / (TT * II);          // 2048
    const int grid = (B + BT - 1) / BT;             // 256 blocks, 1 per CU
    lstm_r4<<<grid, NT, 0, stream>>>(x, W_ih, W_hh, b_ih, b_hh,
                                     W_lin, b_lin, out, B);
}

// Round 5
// 478.018 us; speedup vs baseline: 1.6188x; 1.2132x over previous
//
#include <hip/hip_runtime.h>

// LSTM B=2048,T=512,I=5,H=128 + linear -> [B,1], fp32 in/out.
// Round 5: make the step MFMA-bound. r4 was VALU-bound (55% busy) because the
// cell phase issued 4 cells of 1/4-rate transcendentals on exec-masked half
// waves (320 cyc/wave-step). Now: cells spread over all 64 lanes (2/lane) via
// __shfl_xor(32) redistribution of the C-layout acc (8 bperm + 8 cndmask);
// acc born from the x/bias MFMA with loop-invariant zero C (no 16-mov init);
// hbuf holds only the 8 real batch rows (lanes n>=8 use a zero A-frag, no
// ds_read). MFMA floor: 40 MFMA/SIMD-step x 19.4cyc = 776 cyc (M=8-in-16
// padding is structural: B=2048 fills half of 256CU x M=16; K-split-over-M is
// impossible since MFMA shares B k-indices across all A rows).

#define HH 128
#define II 5
#define TT 512
#define BT 8
#define NT 512
#define KS 136             // hbuf row stride in f16
#define XT (TT * 8 + 8)    // xs per-batch stride in f16

typedef __attribute__((ext_vector_type(8))) _Float16 half8;
typedef __attribute__((ext_vector_type(4))) float f32x4;

__device__ __forceinline__ float sigmoid_f(float x) {
    float e = __builtin_amdgcn_exp2f(x * -1.44269504f);
    return __builtin_amdgcn_rcpf(1.0f + e);
}
__device__ __forceinline__ float tanh_f(float x) {
    float e = __builtin_amdgcn_exp2f(x * 2.88539008f);
    return 1.0f - 2.0f * __builtin_amdgcn_rcpf(1.0f + e);
}

__global__ __launch_bounds__(NT)
__attribute__((amdgpu_waves_per_eu(2, 2)))   // 256-VGPR budget: spill guard
void lstm_r5(const float* __restrict__ x,      // [B,T,I]
             const float* __restrict__ W_ih,   // [4H,I]
             const float* __restrict__ W_hh,   // [4H,H]
             const float* __restrict__ b_ih,   // [4H]
             const float* __restrict__ b_hh,   // [4H]
             const float* __restrict__ W_lin,  // [H]
             const float* __restrict__ b_lin,  // [1]
             float* __restrict__ out,          // [B]
             int B)
{
    __shared__ __align__(16) _Float16 hbuf[2][BT][KS];  // 4.4 KB, 8 real rows
    __shared__ __align__(16) _Float16 xs[BT * XT];      // 65.7 KB
    __shared__ float hsc[BT][HH + 4];                   // final fp32 h

    const int tid  = threadIdx.x;
    const int b0   = blockIdx.x * BT;
    const int lane = tid & 63;
    const int w    = tid >> 6;        // 0..7 -> col group
    const int n    = lane & 15;       // A row (batch) / D col
    const int q    = lane >> 4;
    const int q8   = q * 8;
    const int hcol = w * 16 + n;      // this wave's hj columns

    // ---- W fragments, f16, B-layout (lane holds W^T[k=q8+e][col n]) --------
    half8 wf[4][5];
    #pragma unroll
    for (int g = 0; g < 4; ++g) {
        const int j = g * HH + hcol;
        #pragma unroll
        for (int kc = 0; kc < 4; ++kc) {
            const float* p = W_hh + (size_t)j * HH + kc * 32 + q8;
            #pragma unroll
            for (int e = 0; e < 8; ++e) wf[g][kc][e] = (_Float16)p[e];
        }
        #pragma unroll
        for (int e = 0; e < 8; ++e) {
            const int k = q8 + e;
            float v = 0.0f;
            if (k < II)       v = W_ih[j * II + k];
            else if (k == II) v = b_ih[j] + b_hh[j];
            wf[g][4][e] = (_Float16)v;
        }
    }

    // ---- zero LDS ----------------------------------------------------------
    for (int idx = tid; idx < 2 * BT * KS; idx += NT)
        (&hbuf[0][0][0])[idx] = (_Float16)0.0f;
    for (int idx = tid; idx < BT * XT; idx += NT)
        xs[idx] = (_Float16)0.0f;
    __syncthreads();

    // ---- stage x: 64 threads per batch, float4 global reads ----------------
    {
        const int lb = tid & 63;
        const int bb = tid >> 6;
        if (b0 + bb < B) {
            const float* xb = x + (size_t)(b0 + bb) * TT * II;
            for (int e = lb * 4; e < TT * II; e += 256) {
                float4 v = *reinterpret_cast<const float4*>(xb + e);
                float vv[4] = {v.x, v.y, v.z, v.w};
                #pragma unroll
                for (int u = 0; u < 4; ++u) {
                    const int ee = e + u;
                    const int t_ = ee / 5, i_ = ee % 5;
                    xs[bb * XT + t_ * 8 + i_] = (_Float16)vv[u];
                }
            }
        }
    }
    __syncthreads();

    // cell rows for this lane: m0, m0+1 (all 64 lanes useful)
    const int m0 = (q & 1) * 4 + (q >> 1) * 2;
    float cc[2] = {0.f, 0.f};
    const f32x4 zero4 = {0.f, 0.f, 0.f, 0.f};   // loop-invariant MFMA C seed

    #pragma unroll 1
    for (int t = 0; t < TT; ++t) {
        const int pb = t & 1;

        // x/bias chunk (kc=4) in registers; rows >=8 zero
        half8 ax;
        #pragma unroll
        for (int e = 0; e < 8; ++e) ax[e] = (_Float16)0.0f;
        if (q == 0 && n < BT) {
            ax = *reinterpret_cast<const half8*>(&xs[n * XT + t * 8]);
            ax[5] = (_Float16)1.0f;    // bias column (elems 6,7 are zero pads)
        }

        // acc born from the x/bias MFMA (no zero-init churn)
        f32x4 acc[4];
        #pragma unroll
        for (int g = 0; g < 4; ++g)
            acc[g] = __builtin_amdgcn_mfma_f32_16x16x32_f16(ax, wf[g][4], zero4, 0, 0, 0);

        #pragma unroll
        for (int kc = 0; kc < 4; ++kc) {
            half8 ah;
            #pragma unroll
            for (int e = 0; e < 8; ++e) ah[e] = (_Float16)0.0f;
            if (n < BT)
                ah = *reinterpret_cast<const half8*>(&hbuf[pb][n][kc * 32 + q8]);
            #pragma unroll
            for (int g = 0; g < 4; ++g)
                acc[g] = __builtin_amdgcn_mfma_f32_16x16x32_f16(ah, wf[g][kc], acc[g], 0, 0, 0);
        }

        // redistribute: lanes q<2 keep rows {q*4, q*4+1}; lanes q>=2 take
        // rows {q*4+2, q*4+3} of lane^32 -> every lane owns 2 cells
        float gate[4][2];
        const bool lo = (lane < 32);
        #pragma unroll
        for (int g = 0; g < 4; ++g) {
            float s2 = __shfl_xor(acc[g][2], 32, 64);
            float s3 = __shfl_xor(acc[g][3], 32, 64);
            gate[g][0] = lo ? acc[g][0] : s2;
            gate[g][1] = lo ? acc[g][1] : s3;
        }

        // ---- cell phase: 2 cells/lane, all lanes useful --------------------
        #pragma unroll
        for (int jj = 0; jj < 2; ++jj) {
            const int m = m0 + jj;
            float iv = sigmoid_f(gate[0][jj]);
            float fv = sigmoid_f(gate[1][jj]);
            float gv = tanh_f(gate[2][jj]);
            float ov = sigmoid_f(gate[3][jj]);
            cc[jj] = fv * cc[jj] + iv * gv;
            float hv = ov * tanh_f(cc[jj]);
            hbuf[pb ^ 1][m][hcol] = (_Float16)hv;
            if (t == TT - 1) hsc[m][hcol] = hv;
        }
        __syncthreads();
    }

    // ---- epilogue: out[b0+w] = hsc[w,:] . W_lin + b_lin --------------------
    float p = hsc[w][lane] * W_lin[lane] + hsc[w][lane + 64] * W_lin[lane + 64];
    #pragma unroll
    for (int off = 32; off > 0; off >>= 1) p += __shfl_down(p, off, 64);
    if (lane == 0 && (b0 + w) < B) out[b0 + w] = p + b_lin[0];
}

extern "C" void kernel_launch(void* const* d_in, const int* in_sizes, int n_in,
                              void* d_out, int out_size, void* d_ws, size_t ws_size,
                              hipStream_t stream) {
    const float* x     = (const float*)d_in[0];
    const float* W_ih  = (const float*)d_in[1];
    const float* W_hh  = (const float*)d_in[2];
    const float* b_ih  = (const float*)d_in[3];
    const float* b_hh  = (const float*)d_in[4];
    const float* W_lin = (const float*)d_in[5];
    const float* b_lin = (const float*)d_in[6];
    float* out = (float*)d_out;

    const int B = in_sizes[0] / (TT * II);          // 2048
    const int grid = (B + BT - 1) / BT;             // 256 blocks, 1 per CU
    lstm_r5<<<grid, NT, 0, stream>>>(x, W_ih, W_hh, b_ih, b_hh,
                                     W_lin, b_lin, out, B);
}

// Round 6
// 439.181 us; speedup vs baseline: 1.7620x; 1.0884x over previous
//
#include <hip/hip_runtime.h>

// LSTM B=2048,T=512,I=5,H=128 + linear -> [B,1], fp32 in/out.
// Round 6: lean inner loop. r5 was VALU-bound (50% busy = ~1070 cyc/SIMD-step
// vs ~460 essential): compiler fat from per-iter A-frag re-zeroing, pb address
// math, activation-scale muls, epilogue branch. Fixes: persistent zero A-frag
// registers (masked ds_read leaves inactive lanes' zeros intact), manual
// unroll-by-2 so pb is compile-time (all LDS addrs = 1 VGPR + imm offsets,
// buffer select = +2176B imm), activation scales folded into the f16 W frags
// (sigmoid gates x -log2e, tanh gate x 2log2e -> exp2(acc) directly), bias-1.0
// staged into xs slot 5 (ax = raw ds_read_b128), last timestep peeled (hsc
// path out of the hot loop). Structure (verified r5): wave w owns gate-quad
// cols {g*128+w*16+n}; M=8-in-16 padding structural (B=2048 = half of
// 256CU x M16); 1 barrier/step, dbuf h; cells 2/lane via shfl_xor(32).

#define HH 128
#define II 5
#define TT 512
#define BT 8
#define NT 512
#define KS 136             // hbuf row stride in f16
#define XT (TT * 8 + 8)    // xs per-batch stride in f16

typedef __attribute__((ext_vector_type(8))) _Float16 half8;
typedef __attribute__((ext_vector_type(4))) float f32x4;

#define SIG(u) __builtin_amdgcn_rcpf(1.0f + __builtin_amdgcn_exp2f(u))

// One timestep. PB = h read buffer (compile-time), XOFF = xs elem offset,
// LAST = peeled final step (write fp32 hsc instead of f16 hbuf).
#define STEP(PB, XOFF, LAST) {                                                  \
    if (xmask) ax = *reinterpret_cast<const half8*>(xcur + (XOFF));             \
    if (nmask) {                                                                \
        const _Float16* hp = hrd + (PB) * (BT * KS);                            \
        ah0 = *reinterpret_cast<const half8*>(hp);                              \
        ah1 = *reinterpret_cast<const half8*>(hp + 32);                         \
        ah2 = *reinterpret_cast<const half8*>(hp + 64);                         \
        ah3 = *reinterpret_cast<const half8*>(hp + 96);                         \
    }                                                                           \
    f32x4 acc[4];                                                               \
    _Pragma("unroll")                                                           \
    for (int g = 0; g < 4; ++g) {                                               \
        acc[g] = __builtin_amdgcn_mfma_f32_16x16x32_f16(ax,  wf[g][4], zero4,  0, 0, 0); \
        acc[g] = __builtin_amdgcn_mfma_f32_16x16x32_f16(ah0, wf[g][0], acc[g], 0, 0, 0); \
        acc[g] = __builtin_amdgcn_mfma_f32_16x16x32_f16(ah1, wf[g][1], acc[g], 0, 0, 0); \
        acc[g] = __builtin_amdgcn_mfma_f32_16x16x32_f16(ah2, wf[g][2], acc[g], 0, 0, 0); \
        acc[g] = __builtin_amdgcn_mfma_f32_16x16x32_f16(ah3, wf[g][3], acc[g], 0, 0, 0); \
    }                                                                           \
    float gate[4][2];                                                           \
    _Pragma("unroll")                                                           \
    for (int g = 0; g < 4; ++g) {                                               \
        float s2 = __shfl_xor(acc[g][2], 32, 64);                               \
        float s3 = __shfl_xor(acc[g][3], 32, 64);                               \
        gate[g][0] = lo ? acc[g][0] : s2;                                       \
        gate[g][1] = lo ? acc[g][1] : s3;                                       \
    }                                                                           \
    float iv = SIG(gate[0][0]);                                                 \
    float fv = SIG(gate[1][0]);                                                 \
    float gv = 1.0f - 2.0f * SIG(gate[2][0]);                                   \
    float ov = SIG(gate[3][0]);                                                 \
    cc0 = fv * cc0 + iv * gv;                                                   \
    float hv0 = ov * (1.0f - 2.0f * SIG(2.88539008f * cc0));                    \
    iv = SIG(gate[0][1]);                                                       \
    fv = SIG(gate[1][1]);                                                       \
    gv = 1.0f - 2.0f * SIG(gate[2][1]);                                         \
    ov = SIG(gate[3][1]);                                                       \
    cc1 = fv * cc1 + iv * gv;                                                   \
    float hv1 = ov * (1.0f - 2.0f * SIG(2.88539008f * cc1));                    \
    if (LAST) {                                                                 \
        hsc[m0][hcol] = hv0; hsc[m0 + 1][hcol] = hv1;                           \
    } else {                                                                    \
        _Float16* wp = hwr + (((PB) ^ 1)) * (BT * KS);                          \
        wp[0]  = (_Float16)hv0;                                                 \
        wp[KS] = (_Float16)hv1;                                                 \
    }                                                                           \
    __syncthreads();                                                            \
}

__global__ __launch_bounds__(NT)
__attribute__((amdgpu_waves_per_eu(2, 2)))   // 256-VGPR budget: spill guard
void lstm_r6(const float* __restrict__ x,      // [B,T,I]
             const float* __restrict__ W_ih,   // [4H,I]
             const float* __restrict__ W_hh,   // [4H,H]
             const float* __restrict__ b_ih,   // [4H]
             const float* __restrict__ b_hh,   // [4H]
             const float* __restrict__ W_lin,  // [H]
             const float* __restrict__ b_lin,  // [1]
             float* __restrict__ out,          // [B]
             int B)
{
    __shared__ __align__(16) _Float16 hbuf[2][BT][KS];  // 4.4 KB dbuf h
    __shared__ __align__(16) _Float16 xs[BT * XT];      // 65.7 KB staged x
    __shared__ float hsc[BT][HH + 4];                   // final fp32 h

    const int tid  = threadIdx.x;
    const int b0   = blockIdx.x * BT;
    const int lane = tid & 63;
    const int w    = tid >> 6;        // 0..7 -> col group
    const int n    = lane & 15;       // A row (batch) / D col
    const int q    = lane >> 4;
    const int q8   = q * 8;
    const int hcol = w * 16 + n;      // this wave's hj columns

    // ---- W frags, f16, B-layout, activation scale folded --------------------
    // k<128: W_hh; 128..132: W_ih; 133: bias; 134..159: 0. All x sc(gate).
    half8 wf[4][5];
    #pragma unroll
    for (int g = 0; g < 4; ++g) {
        const float sc = (g == 2) ? 2.88539008f : -1.44269504f;
        const int j = g * HH + hcol;
        #pragma unroll
        for (int kc = 0; kc < 4; ++kc) {
            const float* p = W_hh + (size_t)j * HH + kc * 32 + q8;
            #pragma unroll
            for (int e = 0; e < 8; ++e) wf[g][kc][e] = (_Float16)(p[e] * sc);
        }
        #pragma unroll
        for (int e = 0; e < 8; ++e) {
            const int k = q8 + e;
            float v = 0.0f;
            if (k < II)       v = W_ih[j * II + k];
            else if (k == II) v = b_ih[j] + b_hh[j];
            wf[g][4][e] = (_Float16)(v * sc);
        }
    }

    // ---- zero LDS -----------------------------------------------------------
    for (int idx = tid; idx < 2 * BT * KS; idx += NT)
        (&hbuf[0][0][0])[idx] = (_Float16)0.0f;
    for (int idx = tid; idx < BT * XT; idx += NT)
        xs[idx] = (_Float16)0.0f;
    __syncthreads();

    // ---- stage x (f16) + constant-1.0 bias column in slot 5 -----------------
    {
        const int lb = tid & 63, bb = tid >> 6;
        if (b0 + bb < B) {
            const float* xb = x + (size_t)(b0 + bb) * TT * II;
            for (int e = lb * 4; e < TT * II; e += 256) {
                float4 v = *reinterpret_cast<const float4*>(xb + e);
                float vv[4] = {v.x, v.y, v.z, v.w};
                #pragma unroll
                for (int u = 0; u < 4; ++u) {
                    const int ee = e + u;
                    xs[bb * XT + (ee / 5) * 8 + (ee % 5)] = (_Float16)vv[u];
                }
            }
        }
        for (int s = tid; s < BT * TT; s += NT)
            xs[(s >> 9) * XT + (s & 511) * 8 + 5] = (_Float16)1.0f;
    }
    __syncthreads();

    // ---- loop-invariant state ----------------------------------------------
    const int m0 = (q & 1) * 4 + (q >> 1) * 2;      // cell rows m0, m0+1
    float cc0 = 0.f, cc1 = 0.f;
    const f32x4 zero4 = {0.f, 0.f, 0.f, 0.f};
    const bool nmask = (n < BT);
    const bool xmask = (q == 0) && nmask;
    const bool lo    = (lane < 32);
    const _Float16* hrd = &hbuf[0][0][0] + n * KS + q8;   // + PB*1088 + kc*32 (imm)
    _Float16*       hwr = &hbuf[0][0][0] + m0 * KS + hcol;// + (PB^1)*1088, +KS (imm)
    const _Float16* xcur = &xs[0] + n * XT;               // advances 16/pair

    // persistent A-frags; masked lanes keep these zeros forever
    half8 ax, ah0, ah1, ah2, ah3;
    #pragma unroll
    for (int e = 0; e < 8; ++e) ax[e] = (_Float16)0.0f;
    ah0 = ax; ah1 = ax; ah2 = ax; ah3 = ax;

    #pragma unroll 1
    for (int t = 0; t < TT - 2; t += 2) {
        STEP(0, 0, false);
        STEP(1, 8, false);
        xcur += 16;
    }
    STEP(0, 0, false);     // t = 510
    STEP(1, 8, true);      // t = 511, peeled: writes fp32 hsc

    // ---- epilogue: out[b0+w] = hsc[w,:] . W_lin + b_lin ---------------------
    float p = hsc[w][lane] * W_lin[lane] + hsc[w][lane + 64] * W_lin[lane + 64];
    #pragma unroll
    for (int off = 32; off > 0; off >>= 1) p += __shfl_down(p, off, 64);
    if (lane == 0 && (b0 + w) < B) out[b0 + w] = p + b_lin[0];
}

extern "C" void kernel_launch(void* const* d_in, const int* in_sizes, int n_in,
                              void* d_out, int out_size, void* d_ws, size_t ws_size,
                              hipStream_t stream) {
    const float* x     = (const float*)d_in[0];
    const float* W_ih  = (const float*)d_in[1];
    const float* W_hh  = (const float*)d_in[2];
    const float* b_ih  = (const float*)d_in[3];
    const float* b_hh  = (const float*)d_in[4];
    const float* W_lin = (const float*)d_in[5];
    const float* b_lin = (const float*)d_in[6];
    float* out = (float*)d_out;

    const int B = in_sizes[0] / (TT * II);          // 2048
    const int grid = (B + BT - 1) / BT;             // 256 blocks, 1 per CU
    lstm_r6<<<grid, NT, 0, stream>>>(x, W_ih, W_hh, b_ih, b_hh,
                                     W_lin, b_lin, out, B);
}